// Round 2
// 780.796 us; speedup vs baseline: 1.7167x; 1.7167x over previous
//
#include <hip/hip_runtime.h>
#include <hip/hip_bf16.h>

// MeshConvNet on MI355X (gfx950) — round 8: fix r7's BN-LDS race (keep the pipeline).
// r7 postmortem: absmax 108 — produce(0,0) in the prologue reads ssc/ssb BEFORE the
// barrier that publishes them (threads 256..511 saw garbage scale/bias for chunk 0).
// Fix: barrier_lds() after the ssc/ssb fill, before the prologue produce (BN path only).
// Everything else frozen from r7:
//   (1) A tile double-buffered in LDS -> ONE barrier per chunk; producers write chunk
//       i+1 while MFMAs consume chunk i (wave-level overlap, T5 setprio applicable).
//   (2) B never touches LDS: W (1MB, L2-resident, shared by all 512 blocks) prepped in
//       fragment order [ci][w4][nt][ks][lane][8]; waves load B as coalesced dwordx4.
//       All 8 waves gather (2 ch/thread) -> produce path halved, gather MLP doubled.
//   (3) Per chunk: B loads first, gathers(ci+2) after feature use -> counted vmcnt
//       keeps prefetches in flight across the barrier (barrier_lds never drains vmcnt).

#define B_ 4
#define E_ 16384

typedef short short8 __attribute__((ext_vector_type(8)));
typedef float floatx4 __attribute__((ext_vector_type(4)));

__device__ __forceinline__ float lk(float v) { return v > 0.0f ? v : 0.01f * v; }
__device__ __forceinline__ float b2f(__hip_bfloat16 h) { return __bfloat162float(h); }
__device__ __forceinline__ __hip_bfloat16 f2b(float f) { return __float2bfloat16(f); }

// Barrier that only waits on LDS (lgkmcnt), not in-flight global loads (vmcnt).
__device__ __forceinline__ void barrier_lds() {
    __builtin_amdgcn_fence(__ATOMIC_RELEASE, "workgroup", "local");
    __builtin_amdgcn_s_barrier();
    __builtin_amdgcn_fence(__ATOMIC_ACQUIRE, "workgroup", "local");
}

template <typename TS>
struct Cvt;
template <>
struct Cvt<float> {
    static __device__ __forceinline__ float to(float f) { return f; }
    static __device__ __forceinline__ float from(float s) { return s; }
    static __device__ __forceinline__ void ld2(const float* p, float* o) {
        const float2 v = *reinterpret_cast<const float2*>(p);
        o[0] = v.x; o[1] = v.y;
    }
};
template <>
struct Cvt<__hip_bfloat16> {
    static __device__ __forceinline__ __hip_bfloat16 to(float f) { return f2b(f); }
    static __device__ __forceinline__ float from(__hip_bfloat16 s) { return b2f(s); }
    static __device__ __forceinline__ void ld2(const __hip_bfloat16* p, float* o) {
        union { unsigned u; __hip_bfloat16 h[2]; } v;
        v.u = *reinterpret_cast<const unsigned*>(p);
        o[0] = b2f(v.h[0]); o[1] = b2f(v.h[1]);
    }
};

// ---------------- x [B][128][E] fp32 -> xT [B*E][128] TS ----------------
template <typename TS>
__global__ void k_transpose_x(const float* __restrict__ x, TS* __restrict__ xT) {
    __shared__ float t[32][33];
    const int b = blockIdx.z, c0 = blockIdx.y * 32, e0 = blockIdx.x * 32;
    const int tx = threadIdx.x & 31, ty = threadIdx.x >> 5;
#pragma unroll
    for (int i = 0; i < 4; ++i) {
        const int c = ty + i * 8;
        t[c][tx] = x[((size_t)b * 128 + c0 + c) * E_ + e0 + tx];
    }
    __syncthreads();
#pragma unroll
    for (int i = 0; i < 4; ++i) {
        const int e = ty + i * 8;
        xT[((size_t)b * E_ + e0 + e) * 128 + c0 + tx] = Cvt<TS>::to(t[tx][e]);
    }
}

// ---- W [256][C][7] fp32 -> wf2 in MFMA-fragment order, bf16 hi only ----
// Layout: t = ((ci*4 + w4)*4 + nt)*2 + ks -> 64 lanes x 8 shorts (16B/lane, 1KB/wave).
// Lane (qd*16+l15) holds B[o = w4*64+nt*16+l15][k-in-chunk = (c&7)*8+f], where
// c = ci*8 + ks*4 + qd and f==7 zero-padded.
__global__ void k_prep_w(const float* __restrict__ w, __hip_bfloat16* __restrict__ wf2, int C) {
    const int NCH = C / 8;
    const int idx = blockIdx.x * blockDim.x + threadIdx.x;
    const int lane = idx & 63, t = idx >> 6;
    const int ks = t & 1, nt = (t >> 1) & 3, w4 = (t >> 3) & 3, ci = t >> 5;
    if (ci >= NCH) return;
    const int o = w4 * 64 + nt * 16 + (lane & 15);
    const int c = ci * 8 + ks * 4 + (lane >> 4);
    const float* src = w + ((size_t)o * C + c) * 7;
    __hip_bfloat16* dst = wf2 + (size_t)idx * 8;
#pragma unroll
    for (int f = 0; f < 7; ++f) dst[f] = f2b(src[f]);
    dst[7] = f2b(0.0f);
}

// ---------------- per-channel sum & sumsq of leaky(h), h [B*E][256] ----------------
template <typename TS>
__global__ void k_bn_stats(const TS* __restrict__ h, float* __restrict__ stats) {
    const int c = threadIdx.x;
    const size_t r0 = (size_t)blockIdx.x * 64;  // 1024 blocks x 64 rows
    float s = 0.0f, q = 0.0f;
    for (int r = 0; r < 64; ++r) {
        const float v = lk(Cvt<TS>::from(h[(r0 + r) * 256 + c]));
        s += v;
        q += v * v;
    }
    atomicAdd(&stats[c], s);
    atomicAdd(&stats[256 + c], q);
}

__global__ void k_bn_finalize(const float* __restrict__ stats, const float* __restrict__ gamma,
                              const float* __restrict__ beta, float* __restrict__ scale,
                              float* __restrict__ bias) {
    const int c = threadIdx.x;
    const float n = 1.0f / 65536.0f;
    const float mean = stats[c] * n;
    const float var = stats[256 + c] * n - mean * mean;
    const float inv = rsqrtf(var + 1e-5f);
    const float s = gamma[c] * inv;
    scale[c] = s;
    bias[c] = beta[c] - mean * s;
}

// ---------------- fused gather + features + split-bf16 MFMA GEMM ----------------
// 512 thr = 8 waves, tile 128 edges x 256 outs, chunk = 8 channels (k=64, A = hi+lo).
// ALL waves gather: thread = edge (tid>>2) x quarter (tid&3, 2 channels). A tile is
// double-buffered in LDS; B fragments are loaded per-wave from L2-resident wf2.
// One barrier per chunk.
template <int C, bool BN, typename TS>
__global__ __launch_bounds__(512, 2) void k_conv(const TS* __restrict__ hin,
                                                 const int* __restrict__ edges,
                                                 const __hip_bfloat16* __restrict__ wf2,
                                                 const float* __restrict__ scale,
                                                 const float* __restrict__ bias,
                                                 TS* __restrict__ hout) {
    constexpr int NCH = C / 8;  // chunks
    constexpr int ASA = 136;    // A row stride in shorts: [hi 64 | lo 64 | pad 8]
    __shared__ __align__(16) __hip_bfloat16 Asm[2][128 * ASA];  // 2 x 34816 B
    __shared__ float ssc[256];
    __shared__ float ssb[256];

    const int tid = threadIdx.x;
    const int tm = blockIdx.x;  // 512 m-tiles (128 per batch)
    const int b = tm >> 7;
    const int e0 = (tm & 127) * 128;
    const int wave = tid >> 6, lane = tid & 63;

    if constexpr (BN) {
        if (tid < C) {
            ssc[tid] = scale[tid];
            ssb[tid] = bias[tid];
        }
    }

    // ---- gather assignment: every thread owns (edge, 2 channels)
    const int e_loc = tid >> 2;  // 0..127
    const int q = tid & 3;       // channel pair within 8-ch chunk
    const TS* rp0;
    const TS* rp1;
    const TS* rp2;
    const TS* rp3;
    const TS* rp4;
    {
        const int4 nb =
            *reinterpret_cast<const int4*>(edges + (((size_t)b * E_) + e0 + e_loc) * 4);
        const size_t rb = (size_t)b * E_;
        const int co = q * 2;
        rp0 = hin + (rb + e0 + e_loc) * C + co;
        rp1 = hin + (rb + nb.x) * C + co;
        rp2 = hin + (rb + nb.y) * C + co;
        rp3 = hin + (rb + nb.z) * C + co;
        rp4 = hin + (rb + nb.w) * C + co;
    }

    floatx4 acc[4][4];
#pragma unroll
    for (int i = 0; i < 4; ++i)
#pragma unroll
        for (int j = 0; j < 4; ++j) {
            floatx4 z = {0.0f, 0.0f, 0.0f, 0.0f};
            acc[i][j] = z;
        }

    const int wm = (wave & 1) * 64;
    const int w4 = (wave >> 1) & 3;  // 64-col n-tile
    const int wn = w4 * 64;
    const int qd = lane >> 4, l15 = lane & 15;

    float pf[5][2];
    auto issue_gathers = [&](int cch) {
        const int co = cch * 8;
        Cvt<TS>::ld2(rp0 + co, pf[0]);
        Cvt<TS>::ld2(rp1 + co, pf[1]);
        Cvt<TS>::ld2(rp2 + co, pf[2]);
        Cvt<TS>::ld2(rp3 + co, pf[3]);
        Cvt<TS>::ld2(rp4 + co, pf[4]);
    };
    // pf must hold chunk cch's data; writes features into Asm[bs]
    auto produce = [&](int cch, int bs) {
#pragma unroll
        for (int cc = 0; cc < 2; ++cc) {
            float f0 = pf[0][cc], f1 = pf[1][cc], f2 = pf[2][cc], f3 = pf[3][cc],
                  f4 = pf[4][cc];
            if constexpr (BN) {
                const float sA = ssc[cch * 8 + q * 2 + cc];
                const float bA = ssb[cch * 8 + q * 2 + cc];
                f0 = lk(f0) * sA + bA;
                f1 = lk(f1) * sA + bA;
                f2 = lk(f2) * sA + bA;
                f3 = lk(f3) * sA + bA;
                f4 = lk(f4) * sA + bA;
            }
            float gf[8];
            gf[0] = f0;
            gf[1] = f1 + f3;
            gf[2] = f2 + f4;
            gf[3] = fabsf(f1 - f3);
            gf[4] = fabsf(f2 - f4);
            gf[5] = gf[1] + gf[2];
            const float avg = 0.25f * gf[5];
            const float d1 = f1 - avg, d2 = f2 - avg, d3 = f3 - avg, d4 = f4 - avg;
            gf[6] = d1 * d1 + d2 * d2 + d3 * d3 + d4 * d4;
            gf[7] = 0.0f;
            union U {
                short8 v;
                __hip_bfloat16 h[8];
            } uh, ul;
#pragma unroll
            for (int f = 0; f < 8; ++f) {
                const __hip_bfloat16 hi = f2b(gf[f]);
                uh.h[f] = hi;
                ul.h[f] = f2b(gf[f] - b2f(hi));
            }
            *reinterpret_cast<short8*>(&Asm[bs][e_loc * ASA + (q * 2 + cc) * 8]) = uh.v;
            *reinterpret_cast<short8*>(&Asm[bs][e_loc * ASA + 64 + (q * 2 + cc) * 8]) = ul.v;
        }
    };

    // ---- prologue: chunk 0 into buf 0, chunk 1 gathers in flight
    issue_gathers(0);
    if constexpr (BN) barrier_lds();  // r8 FIX: ssc/ssb must be visible before produce(0,0)
    produce(0, 0);
    issue_gathers(1);
    barrier_lds();  // Asm[0] visible

    for (int ci = 0; ci < NCH; ++ci) {
        const int cur = ci & 1;

        // 1. B fragments for THIS chunk: coalesced 16B/lane from L2-resident wf2.
        short8 bq[2][4];
#pragma unroll
        for (int ks = 0; ks < 2; ++ks)
#pragma unroll
            for (int nt = 0; nt < 4; ++nt)
                bq[ks][nt] = *reinterpret_cast<const short8*>(
                    wf2 + ((((size_t)ci * 4 + w4) * 4 + nt) * 2 + ks) * 512 + lane * 8);

        // 2. produce chunk ci+1 into the other buffer; then refill pf for ci+2
        if (ci + 1 < NCH) {
            produce(ci + 1, cur ^ 1);
            if (ci + 2 < NCH) issue_gathers(ci + 2);
        }

        // 3. fragments + MFMA on current buffer (T5: boost MFMA waves)
        __builtin_amdgcn_s_setprio(1);
#pragma unroll
        for (int ks = 0; ks < 2; ++ks) {
#pragma unroll
            for (int mt = 0; mt < 4; ++mt) {
                const int r = (wm + mt * 16 + l15) * ASA + ks * 32 + qd * 8;
                const short8 ah = *reinterpret_cast<const short8*>(&Asm[cur][r]);
                const short8 al = *reinterpret_cast<const short8*>(&Asm[cur][r + 64]);
#pragma unroll
                for (int nt = 0; nt < 4; ++nt)
                    acc[mt][nt] = __builtin_amdgcn_mfma_f32_16x16x32_bf16(ah, bq[ks][nt],
                                                                          acc[mt][nt], 0, 0, 0);
#pragma unroll
                for (int nt = 0; nt < 4; ++nt)
                    acc[mt][nt] = __builtin_amdgcn_mfma_f32_16x16x32_bf16(al, bq[ks][nt],
                                                                          acc[mt][nt], 0, 0, 0);
            }
        }
        __builtin_amdgcn_s_setprio(0);

        // single barrier: publishes buf[cur^1] writes, retires buf[cur] reads
        barrier_lds();
    }

    // ---- epilogue: C/D layout col = lane&15, row = (lane>>4)*4 + reg
    const size_t orow0 = (size_t)b * E_ + e0;
#pragma unroll
    for (int mt = 0; mt < 4; ++mt) {
#pragma unroll
        for (int nt = 0; nt < 4; ++nt) {
            const int col = wn + nt * 16 + l15;
            const size_t r0 = orow0 + wm + mt * 16 + qd * 4;
#pragma unroll
            for (int r = 0; r < 4; ++r) hout[(r0 + r) * 256 + col] = Cvt<TS>::to(acc[mt][nt][r]);
        }
    }
}

// ---------------- out[b][o][e] = leaky(h + h1), fp32, transposed write ----------------
template <typename TS>
__global__ void k_final(const TS* __restrict__ h, const TS* __restrict__ h1,
                        float* __restrict__ out) {
    __shared__ float t[32][33];
    const int b = blockIdx.z, o0 = blockIdx.y * 32, e0 = blockIdx.x * 32;
    const int tx = threadIdx.x & 31, ty = threadIdx.x >> 5;
#pragma unroll
    for (int i = 0; i < 4; ++i) {
        const int e = ty + i * 8;
        const size_t idx = ((size_t)b * E_ + e0 + e) * 256 + o0 + tx;
        t[e][tx] = lk(Cvt<TS>::from(h[idx]) + Cvt<TS>::from(h1[idx]));
    }
    __syncthreads();
#pragma unroll
    for (int i = 0; i < 4; ++i) {
        const int o = ty + i * 8;
        out[((size_t)b * 256 + o0 + o) * E_ + e0 + tx] = t[tx][o];
    }
}

template <typename TS>
static void run_all(const float* x, const int* edges, const float* W0, const float* Ws,
                    const float* gammas, const float* betas, float* out, char* ws,
                    hipStream_t stream) {
    const size_t hbytes = (size_t)B_ * E_ * 256 * sizeof(TS);
    TS* h1 = (TS*)(ws);
    TS* hA = (TS*)(ws + hbytes);
    TS* hB = (TS*)(ws + 2 * hbytes);
    TS* xT = (TS*)(ws + 2 * hbytes);  // alias hB: dead before conv3 writes hB
    char* wp = ws + 3 * hbytes;
    __hip_bfloat16* wf0 = (__hip_bfloat16*)(wp);  // 512 KB (C=128)
    __hip_bfloat16* wfs[3];
    for (int i = 0; i < 3; ++i)
        wfs[i] = (__hip_bfloat16*)(wp + (512u << 10) + (size_t)i * (1u << 20));  // 1 MB each
    float* stats = (float*)(wp + (4u << 20));
    float* scale = (float*)(wp + (4u << 20) + 2048);
    float* bias = (float*)(wp + (4u << 20) + 3072);

    k_transpose_x<TS><<<dim3(E_ / 32, 4, B_), 256, 0, stream>>>(x, xT);
    k_prep_w<<<128, 256, 0, stream>>>(W0, wf0, 128);
    for (int i = 0; i < 3; ++i)
        k_prep_w<<<256, 256, 0, stream>>>(Ws + (size_t)i * 458752, wfs[i], 256);

    const dim3 gconv(512);
    k_conv<128, false, TS><<<gconv, 512, 0, stream>>>(xT, edges, wf0, nullptr, nullptr, h1);

    TS* bin[3] = {h1, hA, hB};
    TS* bout[3] = {hA, hB, hA};
    for (int i = 0; i < 3; ++i) {
        hipMemsetAsync(stats, 0, 512 * sizeof(float), stream);
        k_bn_stats<TS><<<1024, 256, 0, stream>>>(bin[i], stats);
        k_bn_finalize<<<1, 256, 0, stream>>>(stats, gammas + 256 * i, betas + 256 * i, scale, bias);
        k_conv<256, true, TS><<<gconv, 512, 0, stream>>>(bin[i], edges, wfs[i], scale, bias,
                                                         bout[i]);
    }
    k_final<TS><<<dim3(E_ / 32, 256 / 32, B_), 256, 0, stream>>>(hA, h1, out);
}

extern "C" void kernel_launch(void* const* d_in, const int* in_sizes, int n_in, void* d_out,
                              int out_size, void* d_ws, size_t ws_size, hipStream_t stream) {
    const float* x = (const float*)d_in[0];
    const int* edges = (const int*)d_in[1];
    const float* W0 = (const float*)d_in[2];
    const float* Ws = (const float*)d_in[3];
    const float* gammas = (const float*)d_in[4];
    const float* betas = (const float*)d_in[5];
    float* out = (float*)d_out;
    char* ws = (char*)d_ws;

    // fp32-h path needs 3*64MB + ~4.1MB weights/stats; keep the established threshold.
    if (ws_size >= 208670720ULL + 4096ULL)
        run_all<float>(x, edges, W0, Ws, gammas, betas, out, ws, stream);
    else
        run_all<__hip_bfloat16>(x, edges, W0, Ws, gammas, betas, out, ws, stream);
}

// Round 3
// 766.399 us; speedup vs baseline: 1.7490x; 1.0188x over previous
//
#include <hip/hip_runtime.h>
#include <hip/hip_bf16.h>

// MeshConvNet on MI355X (gfx950) — round 9: 2 blocks/CU via 64x256 tiles.
// r8 postmortem: prediction matched (166us, Mfma 37, VALU 30) but occupancy is stuck at
// 22% — 84 VGPR + 64 acc AGPR = 148 unified regs -> 2 waves/SIMD -> ONE block/CU. The
// remaining ~33% idle (barrier/lgkm/vmcnt) has no other-block work to hide under.
// This round: tile 128x256 -> 64x256 (1024 blocks), wave tile 32x64 -> acc[2][4] = 32
// AGPR, 1 ch/thread produce (half the per-thread VALU), ~112 total regs, LDS 36KB.
// __launch_bounds__(512,4) -> 2 blocks/CU; block B's MFMA fills block A's stalls.
// Pipeline structure (1 barrier/chunk, dbuf A, B from L2 wf2, prefetch gathers +2)
// frozen from r8. Watch: WRITE_SIZE ~65.5MB (spill tripwire), absmax 6.0.

#define B_ 4
#define E_ 16384

typedef short short8 __attribute__((ext_vector_type(8)));
typedef float floatx4 __attribute__((ext_vector_type(4)));

__device__ __forceinline__ float lk(float v) { return v > 0.0f ? v : 0.01f * v; }
__device__ __forceinline__ float b2f(__hip_bfloat16 h) { return __bfloat162float(h); }
__device__ __forceinline__ __hip_bfloat16 f2b(float f) { return __float2bfloat16(f); }

// Barrier that only waits on LDS (lgkmcnt), not in-flight global loads (vmcnt).
__device__ __forceinline__ void barrier_lds() {
    __builtin_amdgcn_fence(__ATOMIC_RELEASE, "workgroup", "local");
    __builtin_amdgcn_s_barrier();
    __builtin_amdgcn_fence(__ATOMIC_ACQUIRE, "workgroup", "local");
}

template <typename TS>
struct Cvt;
template <>
struct Cvt<float> {
    static __device__ __forceinline__ float to(float f) { return f; }
    static __device__ __forceinline__ float from(float s) { return s; }
    static __device__ __forceinline__ float ld1(const float* p) { return *p; }
};
template <>
struct Cvt<__hip_bfloat16> {
    static __device__ __forceinline__ __hip_bfloat16 to(float f) { return f2b(f); }
    static __device__ __forceinline__ float from(__hip_bfloat16 s) { return b2f(s); }
    static __device__ __forceinline__ float ld1(const __hip_bfloat16* p) { return b2f(*p); }
};

// ---------------- x [B][128][E] fp32 -> xT [B*E][128] TS ----------------
template <typename TS>
__global__ void k_transpose_x(const float* __restrict__ x, TS* __restrict__ xT) {
    __shared__ float t[32][33];
    const int b = blockIdx.z, c0 = blockIdx.y * 32, e0 = blockIdx.x * 32;
    const int tx = threadIdx.x & 31, ty = threadIdx.x >> 5;
#pragma unroll
    for (int i = 0; i < 4; ++i) {
        const int c = ty + i * 8;
        t[c][tx] = x[((size_t)b * 128 + c0 + c) * E_ + e0 + tx];
    }
    __syncthreads();
#pragma unroll
    for (int i = 0; i < 4; ++i) {
        const int e = ty + i * 8;
        xT[((size_t)b * E_ + e0 + e) * 128 + c0 + tx] = Cvt<TS>::to(t[tx][e]);
    }
}

// ---- W [256][C][7] fp32 -> wf2 in MFMA-fragment order, bf16 hi only ----
// Layout: t = ((ci*4 + w4)*4 + nt)*2 + ks -> 64 lanes x 8 shorts (16B/lane, 1KB/wave).
// Lane (qd*16+l15) holds B[o = w4*64+nt*16+l15][k-in-chunk = (c&7)*8+f], where
// c = ci*8 + ks*4 + qd and f==7 zero-padded.
__global__ void k_prep_w(const float* __restrict__ w, __hip_bfloat16* __restrict__ wf2, int C) {
    const int NCH = C / 8;
    const int idx = blockIdx.x * blockDim.x + threadIdx.x;
    const int lane = idx & 63, t = idx >> 6;
    const int ks = t & 1, nt = (t >> 1) & 3, w4 = (t >> 3) & 3, ci = t >> 5;
    if (ci >= NCH) return;
    const int o = w4 * 64 + nt * 16 + (lane & 15);
    const int c = ci * 8 + ks * 4 + (lane >> 4);
    const float* src = w + ((size_t)o * C + c) * 7;
    __hip_bfloat16* dst = wf2 + (size_t)idx * 8;
#pragma unroll
    for (int f = 0; f < 7; ++f) dst[f] = f2b(src[f]);
    dst[7] = f2b(0.0f);
}

// ---------------- per-channel sum & sumsq of leaky(h), h [B*E][256] ----------------
template <typename TS>
__global__ void k_bn_stats(const TS* __restrict__ h, float* __restrict__ stats) {
    const int c = threadIdx.x;
    const size_t r0 = (size_t)blockIdx.x * 64;  // 1024 blocks x 64 rows
    float s = 0.0f, q = 0.0f;
    for (int r = 0; r < 64; ++r) {
        const float v = lk(Cvt<TS>::from(h[(r0 + r) * 256 + c]));
        s += v;
        q += v * v;
    }
    atomicAdd(&stats[c], s);
    atomicAdd(&stats[256 + c], q);
}

__global__ void k_bn_finalize(const float* __restrict__ stats, const float* __restrict__ gamma,
                              const float* __restrict__ beta, float* __restrict__ scale,
                              float* __restrict__ bias) {
    const int c = threadIdx.x;
    const float n = 1.0f / 65536.0f;
    const float mean = stats[c] * n;
    const float var = stats[256 + c] * n - mean * mean;
    const float inv = rsqrtf(var + 1e-5f);
    const float s = gamma[c] * inv;
    scale[c] = s;
    bias[c] = beta[c] - mean * s;
}

// ---------------- fused gather + features + split-bf16 MFMA GEMM ----------------
// 512 thr = 8 waves, tile 64 edges x 256 outs, chunk = 8 channels (k=64, A = hi+lo).
// Thread = edge (tid>>3) x channel (tid&7): 1 channel/thread produce. A double-buffered
// in LDS (2 x 17KB); B fragments loaded per-wave from L2-resident wf2. One barrier per
// chunk. Wave tile 32x64: acc[2][4] = 32 AGPR -> 2 blocks/CU at launch_bounds(512,4).
template <int C, bool BN, typename TS>
__global__ __launch_bounds__(512, 4) void k_conv(const TS* __restrict__ hin,
                                                 const int* __restrict__ edges,
                                                 const __hip_bfloat16* __restrict__ wf2,
                                                 const float* __restrict__ scale,
                                                 const float* __restrict__ bias,
                                                 TS* __restrict__ hout) {
    constexpr int NCH = C / 8;  // chunks
    constexpr int ASA = 136;    // A row stride in shorts: [hi 64 | lo 64 | pad 8]
    __shared__ __align__(16) __hip_bfloat16 Asm[2][64 * ASA];  // 2 x 17408 B
    __shared__ float ssc[256];
    __shared__ float ssb[256];

    const int tid = threadIdx.x;
    const int tm = blockIdx.x;  // 1024 m-tiles (256 per batch)
    const int b = tm >> 8;
    const int e0 = (tm & 255) * 64;
    const int wave = tid >> 6, lane = tid & 63;

    if constexpr (BN) {
        if (tid < C) {
            ssc[tid] = scale[tid];
            ssb[tid] = bias[tid];
        }
    }

    // ---- gather assignment: every thread owns (edge, 1 channel)
    const int e_loc = tid >> 3;  // 0..63
    const int ch = tid & 7;      // channel within 8-ch chunk
    const TS* rp0;
    const TS* rp1;
    const TS* rp2;
    const TS* rp3;
    const TS* rp4;
    {
        const int4 nb =
            *reinterpret_cast<const int4*>(edges + (((size_t)b * E_) + e0 + e_loc) * 4);
        const size_t rb = (size_t)b * E_;
        rp0 = hin + (rb + e0 + e_loc) * C + ch;
        rp1 = hin + (rb + nb.x) * C + ch;
        rp2 = hin + (rb + nb.y) * C + ch;
        rp3 = hin + (rb + nb.z) * C + ch;
        rp4 = hin + (rb + nb.w) * C + ch;
    }

    floatx4 acc[2][4];
#pragma unroll
    for (int i = 0; i < 2; ++i)
#pragma unroll
        for (int j = 0; j < 4; ++j) {
            floatx4 z = {0.0f, 0.0f, 0.0f, 0.0f};
            acc[i][j] = z;
        }

    const int wm = (wave & 1) * 32;
    const int w4 = wave >> 1;  // 0..3: 64-col n-tile
    const int wn = w4 * 64;
    const int qd = lane >> 4, l15 = lane & 15;

    float pf[5];
    auto issue_gathers = [&](int cch) {
        const int co = cch * 8;
        pf[0] = Cvt<TS>::ld1(rp0 + co);
        pf[1] = Cvt<TS>::ld1(rp1 + co);
        pf[2] = Cvt<TS>::ld1(rp2 + co);
        pf[3] = Cvt<TS>::ld1(rp3 + co);
        pf[4] = Cvt<TS>::ld1(rp4 + co);
    };
    // pf must hold chunk cch's data; writes features into Asm[bs]
    auto produce = [&](int cch, int bs) {
        float f0 = pf[0], f1 = pf[1], f2 = pf[2], f3 = pf[3], f4 = pf[4];
        if constexpr (BN) {
            const float sA = ssc[cch * 8 + ch];
            const float bA = ssb[cch * 8 + ch];
            f0 = lk(f0) * sA + bA;
            f1 = lk(f1) * sA + bA;
            f2 = lk(f2) * sA + bA;
            f3 = lk(f3) * sA + bA;
            f4 = lk(f4) * sA + bA;
        }
        float gf[8];
        gf[0] = f0;
        gf[1] = f1 + f3;
        gf[2] = f2 + f4;
        gf[3] = fabsf(f1 - f3);
        gf[4] = fabsf(f2 - f4);
        gf[5] = gf[1] + gf[2];
        const float avg = 0.25f * gf[5];
        const float d1 = f1 - avg, d2 = f2 - avg, d3 = f3 - avg, d4 = f4 - avg;
        gf[6] = d1 * d1 + d2 * d2 + d3 * d3 + d4 * d4;
        gf[7] = 0.0f;
        union U {
            short8 v;
            __hip_bfloat16 h[8];
        } uh, ul;
#pragma unroll
        for (int f = 0; f < 8; ++f) {
            const __hip_bfloat16 hi = f2b(gf[f]);
            uh.h[f] = hi;
            ul.h[f] = f2b(gf[f] - b2f(hi));
        }
        *reinterpret_cast<short8*>(&Asm[bs][e_loc * ASA + ch * 8]) = uh.v;
        *reinterpret_cast<short8*>(&Asm[bs][e_loc * ASA + 64 + ch * 8]) = ul.v;
    };

    // ---- prologue: chunk 0 into buf 0, chunk 1 gathers in flight
    issue_gathers(0);
    if constexpr (BN) barrier_lds();  // ssc/ssb must be visible before produce(0,0)
    produce(0, 0);
    issue_gathers(1);
    barrier_lds();  // Asm[0] visible

    for (int ci = 0; ci < NCH; ++ci) {
        const int cur = ci & 1;

        // 1. B fragments for THIS chunk: coalesced 16B/lane from L2-resident wf2.
        short8 bq[2][4];
#pragma unroll
        for (int ks = 0; ks < 2; ++ks)
#pragma unroll
            for (int nt = 0; nt < 4; ++nt)
                bq[ks][nt] = *reinterpret_cast<const short8*>(
                    wf2 + ((((size_t)ci * 4 + w4) * 4 + nt) * 2 + ks) * 512 + lane * 8);

        // 2. produce chunk ci+1 into the other buffer; then refill pf for ci+2
        if (ci + 1 < NCH) {
            produce(ci + 1, cur ^ 1);
            if (ci + 2 < NCH) issue_gathers(ci + 2);
        }

        // 3. fragments + MFMA on current buffer (T5: boost MFMA waves)
        __builtin_amdgcn_s_setprio(1);
#pragma unroll
        for (int ks = 0; ks < 2; ++ks) {
#pragma unroll
            for (int mt = 0; mt < 2; ++mt) {
                const int r = (wm + mt * 16 + l15) * ASA + ks * 32 + qd * 8;
                const short8 ah = *reinterpret_cast<const short8*>(&Asm[cur][r]);
                const short8 al = *reinterpret_cast<const short8*>(&Asm[cur][r + 64]);
#pragma unroll
                for (int nt = 0; nt < 4; ++nt)
                    acc[mt][nt] = __builtin_amdgcn_mfma_f32_16x16x32_bf16(ah, bq[ks][nt],
                                                                          acc[mt][nt], 0, 0, 0);
#pragma unroll
                for (int nt = 0; nt < 4; ++nt)
                    acc[mt][nt] = __builtin_amdgcn_mfma_f32_16x16x32_bf16(al, bq[ks][nt],
                                                                          acc[mt][nt], 0, 0, 0);
            }
        }
        __builtin_amdgcn_s_setprio(0);

        // single barrier: publishes buf[cur^1] writes, retires buf[cur] reads
        barrier_lds();
    }

    // ---- epilogue: C/D layout col = lane&15, row = (lane>>4)*4 + reg
    const size_t orow0 = (size_t)b * E_ + e0;
#pragma unroll
    for (int mt = 0; mt < 2; ++mt) {
#pragma unroll
        for (int nt = 0; nt < 4; ++nt) {
            const int col = wn + nt * 16 + l15;
            const size_t r0 = orow0 + wm + mt * 16 + qd * 4;
#pragma unroll
            for (int r = 0; r < 4; ++r) hout[(r0 + r) * 256 + col] = Cvt<TS>::to(acc[mt][nt][r]);
        }
    }
}

// ---------------- out[b][o][e] = leaky(h + h1), fp32, transposed write ----------------
template <typename TS>
__global__ void k_final(const TS* __restrict__ h, const TS* __restrict__ h1,
                        float* __restrict__ out) {
    __shared__ float t[32][33];
    const int b = blockIdx.z, o0 = blockIdx.y * 32, e0 = blockIdx.x * 32;
    const int tx = threadIdx.x & 31, ty = threadIdx.x >> 5;
#pragma unroll
    for (int i = 0; i < 4; ++i) {
        const int e = ty + i * 8;
        const size_t idx = ((size_t)b * E_ + e0 + e) * 256 + o0 + tx;
        t[e][tx] = lk(Cvt<TS>::from(h[idx]) + Cvt<TS>::from(h1[idx]));
    }
    __syncthreads();
#pragma unroll
    for (int i = 0; i < 4; ++i) {
        const int o = ty + i * 8;
        out[((size_t)b * 256 + o0 + o) * E_ + e0 + tx] = t[tx][o];
    }
}

template <typename TS>
static void run_all(const float* x, const int* edges, const float* W0, const float* Ws,
                    const float* gammas, const float* betas, float* out, char* ws,
                    hipStream_t stream) {
    const size_t hbytes = (size_t)B_ * E_ * 256 * sizeof(TS);
    TS* h1 = (TS*)(ws);
    TS* hA = (TS*)(ws + hbytes);
    TS* hB = (TS*)(ws + 2 * hbytes);
    TS* xT = (TS*)(ws + 2 * hbytes);  // alias hB: dead before conv3 writes hB
    char* wp = ws + 3 * hbytes;
    __hip_bfloat16* wf0 = (__hip_bfloat16*)(wp);  // 512 KB (C=128)
    __hip_bfloat16* wfs[3];
    for (int i = 0; i < 3; ++i)
        wfs[i] = (__hip_bfloat16*)(wp + (512u << 10) + (size_t)i * (1u << 20));  // 1 MB each
    float* stats = (float*)(wp + (4u << 20));
    float* scale = (float*)(wp + (4u << 20) + 2048);
    float* bias = (float*)(wp + (4u << 20) + 3072);

    k_transpose_x<TS><<<dim3(E_ / 32, 4, B_), 256, 0, stream>>>(x, xT);
    k_prep_w<<<128, 256, 0, stream>>>(W0, wf0, 128);
    for (int i = 0; i < 3; ++i)
        k_prep_w<<<256, 256, 0, stream>>>(Ws + (size_t)i * 458752, wfs[i], 256);

    const dim3 gconv(1024);
    k_conv<128, false, TS><<<gconv, 512, 0, stream>>>(xT, edges, wf0, nullptr, nullptr, h1);

    TS* bin[3] = {h1, hA, hB};
    TS* bout[3] = {hA, hB, hA};
    for (int i = 0; i < 3; ++i) {
        hipMemsetAsync(stats, 0, 512 * sizeof(float), stream);
        k_bn_stats<TS><<<1024, 256, 0, stream>>>(bin[i], stats);
        k_bn_finalize<<<1, 256, 0, stream>>>(stats, gammas + 256 * i, betas + 256 * i, scale, bias);
        k_conv<256, true, TS><<<gconv, 512, 0, stream>>>(bin[i], edges, wfs[i], scale, bias,
                                                         bout[i]);
    }
    k_final<TS><<<dim3(E_ / 32, 256 / 32, B_), 256, 0, stream>>>(hA, h1, out);
}

extern "C" void kernel_launch(void* const* d_in, const int* in_sizes, int n_in, void* d_out,
                              int out_size, void* d_ws, size_t ws_size, hipStream_t stream) {
    const float* x = (const float*)d_in[0];
    const int* edges = (const int*)d_in[1];
    const float* W0 = (const float*)d_in[2];
    const float* Ws = (const float*)d_in[3];
    const float* gammas = (const float*)d_in[4];
    const float* betas = (const float*)d_in[5];
    float* out = (float*)d_out;
    char* ws = (char*)d_ws;

    // fp32-h path needs 3*64MB + ~4.1MB weights/stats; keep the established threshold.
    if (ws_size >= 208670720ULL + 4096ULL)
        run_all<float>(x, edges, W0, Ws, gammas, betas, out, ws, stream);
    else
        run_all<__hip_bfloat16>(x, edges, W0, Ws, gammas, betas, out, ws, stream);
}

// Round 4
// 658.697 us; speedup vs baseline: 2.0349x; 1.1635x over previous
//
#include <hip/hip_runtime.h>
#include <hip/hip_bf16.h>

// MeshConvNet on MI355X (gfx950) — round 10: drop the A-lo product (halve MFMA).
// r9 postmortem: occupancy 22->39% bought only 5% (166->158us). Arithmetic: per-CU MFMA
// work with the hi+lo split is ~2490 cyc/chunk-pair vs ~5900 measured — the split A is
// itself half the matrix-pipe work, floor 66us/conv. absmax is 6.0 vs threshold 19.6,
// and B is ALREADY single-bf16 — the same-order rounding error is already accepted.
// This round: A = single bf16 (hi only). MFMA floor 66->33us, produce loses the
// lo-extraction chain (~24 VALU), A-LDS traffic and ds_reads halve (ASA 136->72).
// Predicted absmax ~9-13 (<19.6) — this is the round's bet.
// Pipeline frozen from r9: 64x256 tiles, 1 barrier/chunk, dbuf A, B from L2 wf2,
// prefetch gathers +2, launch_bounds(512,4) = 2 blocks/CU.

#define B_ 4
#define E_ 16384

typedef short short8 __attribute__((ext_vector_type(8)));
typedef float floatx4 __attribute__((ext_vector_type(4)));

__device__ __forceinline__ float lk(float v) { return v > 0.0f ? v : 0.01f * v; }
__device__ __forceinline__ float b2f(__hip_bfloat16 h) { return __bfloat162float(h); }
__device__ __forceinline__ __hip_bfloat16 f2b(float f) { return __float2bfloat16(f); }

// Barrier that only waits on LDS (lgkmcnt), not in-flight global loads (vmcnt).
__device__ __forceinline__ void barrier_lds() {
    __builtin_amdgcn_fence(__ATOMIC_RELEASE, "workgroup", "local");
    __builtin_amdgcn_s_barrier();
    __builtin_amdgcn_fence(__ATOMIC_ACQUIRE, "workgroup", "local");
}

template <typename TS>
struct Cvt;
template <>
struct Cvt<float> {
    static __device__ __forceinline__ float to(float f) { return f; }
    static __device__ __forceinline__ float from(float s) { return s; }
    static __device__ __forceinline__ float ld1(const float* p) { return *p; }
};
template <>
struct Cvt<__hip_bfloat16> {
    static __device__ __forceinline__ __hip_bfloat16 to(float f) { return f2b(f); }
    static __device__ __forceinline__ float from(__hip_bfloat16 s) { return b2f(s); }
    static __device__ __forceinline__ float ld1(const __hip_bfloat16* p) { return b2f(*p); }
};

// ---------------- x [B][128][E] fp32 -> xT [B*E][128] TS ----------------
template <typename TS>
__global__ void k_transpose_x(const float* __restrict__ x, TS* __restrict__ xT) {
    __shared__ float t[32][33];
    const int b = blockIdx.z, c0 = blockIdx.y * 32, e0 = blockIdx.x * 32;
    const int tx = threadIdx.x & 31, ty = threadIdx.x >> 5;
#pragma unroll
    for (int i = 0; i < 4; ++i) {
        const int c = ty + i * 8;
        t[c][tx] = x[((size_t)b * 128 + c0 + c) * E_ + e0 + tx];
    }
    __syncthreads();
#pragma unroll
    for (int i = 0; i < 4; ++i) {
        const int e = ty + i * 8;
        xT[((size_t)b * E_ + e0 + e) * 128 + c0 + tx] = Cvt<TS>::to(t[tx][e]);
    }
}

// ---- W [256][C][7] fp32 -> wf2 in MFMA-fragment order, bf16 hi only ----
// Layout: t = ((ci*4 + w4)*4 + nt)*2 + ks -> 64 lanes x 8 shorts (16B/lane, 1KB/wave).
// Lane (qd*16+l15) holds B[o = w4*64+nt*16+l15][k-in-chunk = (c&7)*8+f], where
// c = ci*8 + ks*4 + qd and f==7 zero-padded.
__global__ void k_prep_w(const float* __restrict__ w, __hip_bfloat16* __restrict__ wf2, int C) {
    const int NCH = C / 8;
    const int idx = blockIdx.x * blockDim.x + threadIdx.x;
    const int lane = idx & 63, t = idx >> 6;
    const int ks = t & 1, nt = (t >> 1) & 3, w4 = (t >> 3) & 3, ci = t >> 5;
    if (ci >= NCH) return;
    const int o = w4 * 64 + nt * 16 + (lane & 15);
    const int c = ci * 8 + ks * 4 + (lane >> 4);
    const float* src = w + ((size_t)o * C + c) * 7;
    __hip_bfloat16* dst = wf2 + (size_t)idx * 8;
#pragma unroll
    for (int f = 0; f < 7; ++f) dst[f] = f2b(src[f]);
    dst[7] = f2b(0.0f);
}

// ---------------- per-channel sum & sumsq of leaky(h), h [B*E][256] ----------------
template <typename TS>
__global__ void k_bn_stats(const TS* __restrict__ h, float* __restrict__ stats) {
    const int c = threadIdx.x;
    const size_t r0 = (size_t)blockIdx.x * 64;  // 1024 blocks x 64 rows
    float s = 0.0f, q = 0.0f;
    for (int r = 0; r < 64; ++r) {
        const float v = lk(Cvt<TS>::from(h[(r0 + r) * 256 + c]));
        s += v;
        q += v * v;
    }
    atomicAdd(&stats[c], s);
    atomicAdd(&stats[256 + c], q);
}

__global__ void k_bn_finalize(const float* __restrict__ stats, const float* __restrict__ gamma,
                              const float* __restrict__ beta, float* __restrict__ scale,
                              float* __restrict__ bias) {
    const int c = threadIdx.x;
    const float n = 1.0f / 65536.0f;
    const float mean = stats[c] * n;
    const float var = stats[256 + c] * n - mean * mean;
    const float inv = rsqrtf(var + 1e-5f);
    const float s = gamma[c] * inv;
    scale[c] = s;
    bias[c] = beta[c] - mean * s;
}

// ---------------- fused gather + features + bf16 MFMA GEMM ----------------
// 512 thr = 8 waves, tile 64 edges x 256 outs, chunk = 8 channels (k=64, A = bf16).
// Thread = edge (tid>>3) x channel (tid&7). A double-buffered in LDS (2 x 9.2KB);
// B fragments loaded per-wave from L2-resident wf2. One barrier per chunk.
// Wave tile 32x64: acc[2][4] = 32 AGPR -> 2 blocks/CU at launch_bounds(512,4).
template <int C, bool BN, typename TS>
__global__ __launch_bounds__(512, 4) void k_conv(const TS* __restrict__ hin,
                                                 const int* __restrict__ edges,
                                                 const __hip_bfloat16* __restrict__ wf2,
                                                 const float* __restrict__ scale,
                                                 const float* __restrict__ bias,
                                                 TS* __restrict__ hout) {
    constexpr int NCH = C / 8;  // chunks
    constexpr int ASA = 72;     // A row stride in shorts: [hi 64 | pad 8]
    __shared__ __align__(16) __hip_bfloat16 Asm[2][64 * ASA];  // 2 x 9216 B
    __shared__ float ssc[256];
    __shared__ float ssb[256];

    const int tid = threadIdx.x;
    const int tm = blockIdx.x;  // 1024 m-tiles (256 per batch)
    const int b = tm >> 8;
    const int e0 = (tm & 255) * 64;
    const int wave = tid >> 6, lane = tid & 63;

    if constexpr (BN) {
        if (tid < C) {
            ssc[tid] = scale[tid];
            ssb[tid] = bias[tid];
        }
    }

    // ---- gather assignment: every thread owns (edge, 1 channel)
    const int e_loc = tid >> 3;  // 0..63
    const int ch = tid & 7;      // channel within 8-ch chunk
    const TS* rp0;
    const TS* rp1;
    const TS* rp2;
    const TS* rp3;
    const TS* rp4;
    {
        const int4 nb =
            *reinterpret_cast<const int4*>(edges + (((size_t)b * E_) + e0 + e_loc) * 4);
        const size_t rb = (size_t)b * E_;
        rp0 = hin + (rb + e0 + e_loc) * C + ch;
        rp1 = hin + (rb + nb.x) * C + ch;
        rp2 = hin + (rb + nb.y) * C + ch;
        rp3 = hin + (rb + nb.z) * C + ch;
        rp4 = hin + (rb + nb.w) * C + ch;
    }

    floatx4 acc[2][4];
#pragma unroll
    for (int i = 0; i < 2; ++i)
#pragma unroll
        for (int j = 0; j < 4; ++j) {
            floatx4 z = {0.0f, 0.0f, 0.0f, 0.0f};
            acc[i][j] = z;
        }

    const int wm = (wave & 1) * 32;
    const int w4 = wave >> 1;  // 0..3: 64-col n-tile
    const int wn = w4 * 64;
    const int qd = lane >> 4, l15 = lane & 15;

    float pf[5];
    auto issue_gathers = [&](int cch) {
        const int co = cch * 8;
        pf[0] = Cvt<TS>::ld1(rp0 + co);
        pf[1] = Cvt<TS>::ld1(rp1 + co);
        pf[2] = Cvt<TS>::ld1(rp2 + co);
        pf[3] = Cvt<TS>::ld1(rp3 + co);
        pf[4] = Cvt<TS>::ld1(rp4 + co);
    };
    // pf must hold chunk cch's data; writes features into Asm[bs]
    auto produce = [&](int cch, int bs) {
        float f0 = pf[0], f1 = pf[1], f2 = pf[2], f3 = pf[3], f4 = pf[4];
        if constexpr (BN) {
            const float sA = ssc[cch * 8 + ch];
            const float bA = ssb[cch * 8 + ch];
            f0 = lk(f0) * sA + bA;
            f1 = lk(f1) * sA + bA;
            f2 = lk(f2) * sA + bA;
            f3 = lk(f3) * sA + bA;
            f4 = lk(f4) * sA + bA;
        }
        float gf[8];
        gf[0] = f0;
        gf[1] = f1 + f3;
        gf[2] = f2 + f4;
        gf[3] = fabsf(f1 - f3);
        gf[4] = fabsf(f2 - f4);
        gf[5] = gf[1] + gf[2];
        const float avg = 0.25f * gf[5];
        const float d1 = f1 - avg, d2 = f2 - avg, d3 = f3 - avg, d4 = f4 - avg;
        gf[6] = d1 * d1 + d2 * d2 + d3 * d3 + d4 * d4;
        gf[7] = 0.0f;
        union U {
            short8 v;
            __hip_bfloat16 h[8];
        } uh;
#pragma unroll
        for (int f = 0; f < 8; ++f) uh.h[f] = f2b(gf[f]);
        *reinterpret_cast<short8*>(&Asm[bs][e_loc * ASA + ch * 8]) = uh.v;
    };

    // ---- prologue: chunk 0 into buf 0, chunk 1 gathers in flight
    issue_gathers(0);
    if constexpr (BN) barrier_lds();  // ssc/ssb must be visible before produce(0,0)
    produce(0, 0);
    issue_gathers(1);
    barrier_lds();  // Asm[0] visible

    for (int ci = 0; ci < NCH; ++ci) {
        const int cur = ci & 1;

        // 1. B fragments for THIS chunk: coalesced 16B/lane from L2-resident wf2.
        short8 bq[2][4];
#pragma unroll
        for (int ks = 0; ks < 2; ++ks)
#pragma unroll
            for (int nt = 0; nt < 4; ++nt)
                bq[ks][nt] = *reinterpret_cast<const short8*>(
                    wf2 + ((((size_t)ci * 4 + w4) * 4 + nt) * 2 + ks) * 512 + lane * 8);

        // 2. produce chunk ci+1 into the other buffer; then refill pf for ci+2
        if (ci + 1 < NCH) {
            produce(ci + 1, cur ^ 1);
            if (ci + 2 < NCH) issue_gathers(ci + 2);
        }

        // 3. fragments + MFMA on current buffer (T5: boost MFMA waves)
        __builtin_amdgcn_s_setprio(1);
#pragma unroll
        for (int ks = 0; ks < 2; ++ks) {
#pragma unroll
            for (int mt = 0; mt < 2; ++mt) {
                const int r = (wm + mt * 16 + l15) * ASA + ks * 32 + qd * 8;
                const short8 ah = *reinterpret_cast<const short8*>(&Asm[cur][r]);
#pragma unroll
                for (int nt = 0; nt < 4; ++nt)
                    acc[mt][nt] = __builtin_amdgcn_mfma_f32_16x16x32_bf16(ah, bq[ks][nt],
                                                                          acc[mt][nt], 0, 0, 0);
            }
        }
        __builtin_amdgcn_s_setprio(0);

        // single barrier: publishes buf[cur^1] writes, retires buf[cur] reads
        barrier_lds();
    }

    // ---- epilogue: C/D layout col = lane&15, row = (lane>>4)*4 + reg
    const size_t orow0 = (size_t)b * E_ + e0;
#pragma unroll
    for (int mt = 0; mt < 2; ++mt) {
#pragma unroll
        for (int nt = 0; nt < 4; ++nt) {
            const int col = wn + nt * 16 + l15;
            const size_t r0 = orow0 + wm + mt * 16 + qd * 4;
#pragma unroll
            for (int r = 0; r < 4; ++r) hout[(r0 + r) * 256 + col] = Cvt<TS>::to(acc[mt][nt][r]);
        }
    }
}

// ---------------- out[b][o][e] = leaky(h + h1), fp32, transposed write ----------------
template <typename TS>
__global__ void k_final(const TS* __restrict__ h, const TS* __restrict__ h1,
                        float* __restrict__ out) {
    __shared__ float t[32][33];
    const int b = blockIdx.z, o0 = blockIdx.y * 32, e0 = blockIdx.x * 32;
    const int tx = threadIdx.x & 31, ty = threadIdx.x >> 5;
#pragma unroll
    for (int i = 0; i < 4; ++i) {
        const int e = ty + i * 8;
        const size_t idx = ((size_t)b * E_ + e0 + e) * 256 + o0 + tx;
        t[e][tx] = lk(Cvt<TS>::from(h[idx]) + Cvt<TS>::from(h1[idx]));
    }
    __syncthreads();
#pragma unroll
    for (int i = 0; i < 4; ++i) {
        const int o = ty + i * 8;
        out[((size_t)b * 256 + o0 + o) * E_ + e0 + tx] = t[tx][o];
    }
}

template <typename TS>
static void run_all(const float* x, const int* edges, const float* W0, const float* Ws,
                    const float* gammas, const float* betas, float* out, char* ws,
                    hipStream_t stream) {
    const size_t hbytes = (size_t)B_ * E_ * 256 * sizeof(TS);
    TS* h1 = (TS*)(ws);
    TS* hA = (TS*)(ws + hbytes);
    TS* hB = (TS*)(ws + 2 * hbytes);
    TS* xT = (TS*)(ws + 2 * hbytes);  // alias hB: dead before conv3 writes hB
    char* wp = ws + 3 * hbytes;
    __hip_bfloat16* wf0 = (__hip_bfloat16*)(wp);  // 512 KB (C=128)
    __hip_bfloat16* wfs[3];
    for (int i = 0; i < 3; ++i)
        wfs[i] = (__hip_bfloat16*)(wp + (512u << 10) + (size_t)i * (1u << 20));  // 1 MB each
    float* stats = (float*)(wp + (4u << 20));
    float* scale = (float*)(wp + (4u << 20) + 2048);
    float* bias = (float*)(wp + (4u << 20) + 3072);

    k_transpose_x<TS><<<dim3(E_ / 32, 4, B_), 256, 0, stream>>>(x, xT);
    k_prep_w<<<128, 256, 0, stream>>>(W0, wf0, 128);
    for (int i = 0; i < 3; ++i)
        k_prep_w<<<256, 256, 0, stream>>>(Ws + (size_t)i * 458752, wfs[i], 256);

    const dim3 gconv(1024);
    k_conv<128, false, TS><<<gconv, 512, 0, stream>>>(xT, edges, wf0, nullptr, nullptr, h1);

    TS* bin[3] = {h1, hA, hB};
    TS* bout[3] = {hA, hB, hA};
    for (int i = 0; i < 3; ++i) {
        hipMemsetAsync(stats, 0, 512 * sizeof(float), stream);
        k_bn_stats<TS><<<1024, 256, 0, stream>>>(bin[i], stats);
        k_bn_finalize<<<1, 256, 0, stream>>>(stats, gammas + 256 * i, betas + 256 * i, scale, bias);
        k_conv<256, true, TS><<<gconv, 512, 0, stream>>>(bin[i], edges, wfs[i], scale, bias,
                                                         bout[i]);
    }
    k_final<TS><<<dim3(E_ / 32, 256 / 32, B_), 256, 0, stream>>>(hA, h1, out);
}

extern "C" void kernel_launch(void* const* d_in, const int* in_sizes, int n_in, void* d_out,
                              int out_size, void* d_ws, size_t ws_size, hipStream_t stream) {
    const float* x = (const float*)d_in[0];
    const int* edges = (const int*)d_in[1];
    const float* W0 = (const float*)d_in[2];
    const float* Ws = (const float*)d_in[3];
    const float* gammas = (const float*)d_in[4];
    const float* betas = (const float*)d_in[5];
    float* out = (float*)d_out;
    char* ws = (char*)d_ws;

    // fp32-h path needs 3*64MB + ~4.1MB weights/stats; keep the established threshold.
    if (ws_size >= 208670720ULL + 4096ULL)
        run_all<float>(x, edges, W0, Ws, gammas, betas, out, ws, stream);
    else
        run_all<__hip_bfloat16>(x, edges, W0, Ws, gammas, betas, out, ws, stream);
}